// Round 9
// baseline (364.285 us; speedup 1.0000x reference)
//
#include <hip/hip_runtime.h>
#include <cstdint>
#include <cstddef>

typedef _Float16 f16;
typedef _Float16 f16x8 __attribute__((ext_vector_type(8)));
typedef float f32x4 __attribute__((ext_vector_type(4)));

// ---------------- helpers ----------------

__device__ __forceinline__ void gload16(const void* g, void* l) {
  // async global->LDS, 16B per lane; LDS dest must be wave-uniform base + lane*16
  __builtin_amdgcn_global_load_lds((const __attribute__((address_space(1))) void*)g,
                                   (__attribute__((address_space(3))) void*)l, 16, 0, 0);
}

__device__ __forceinline__ uint32_t packh2(float a, float b) {
  f16 ha = (f16)a, hb = (f16)b;
  uint16_t ua = __builtin_bit_cast(uint16_t, ha);
  uint16_t ub = __builtin_bit_cast(uint16_t, hb);
  return (uint32_t)ua | ((uint32_t)ub << 16);
}

// ---------------- prep: LUT^T fp16, centroid sq-norms, BN consts, pool zero ----------------
__global__ __launch_bounds__(256) void prep_kernel(
    const float* __restrict__ cent1, const float* __restrict__ wsub1,
    const float* __restrict__ cent2, const float* __restrict__ wsub2,
    const float* __restrict__ g1, const float* __restrict__ be1,
    const float* __restrict__ mu1, const float* __restrict__ va1,
    const float* __restrict__ g2, const float* __restrict__ be2,
    const float* __restrict__ mu2, const float* __restrict__ va2,
    f16* __restrict__ lut1T, f16* __restrict__ lut2T,
    float* __restrict__ cn1, float* __restrict__ cn2,
    float* __restrict__ bn1i, float* __restrict__ bn1a,
    float* __restrict__ bn2i, float* __restrict__ bn2a,
    float* __restrict__ pool)
{
  int bx = blockIdx.x, t = threadIdx.x;
  if (bx < 512) {
    int conv = bx >> 8, o = bx & 255;
    const float* cent = conv ? cent2 : cent1;
    const float* wsub = conv ? wsub2 : wsub1;
    f16* lutT = conv ? lut2T : lut1T;
    float wcol[9];
#pragma unroll
    for (int s = 0; s < 9; ++s) wcol[s] = wsub[(t*9 + s)*256 + o];
    uint32_t u[8];
#pragma unroll
    for (int k2 = 0; k2 < 8; ++k2) {
      float d0 = 0.f, d1 = 0.f;
#pragma unroll
      for (int s = 0; s < 9; ++s) {
        d0 += cent[(t*16 + 2*k2    )*9 + s]*wcol[s];
        d1 += cent[(t*16 + 2*k2 + 1)*9 + s]*wcol[s];
      }
      u[k2] = packh2(d0, d1);
    }
    uint4* dst = (uint4*)(lutT + (size_t)o*4096 + t*16);
    dst[0] = make_uint4(u[0], u[1], u[2], u[3]);
    dst[1] = make_uint4(u[4], u[5], u[6], u[7]);
  } else {
    for (int j = 0; j < 16; ++j) {
      int ck = j*256 + t;
      float s1 = 0.f, s2 = 0.f;
#pragma unroll
      for (int sv = 0; sv < 9; ++sv) {
        float a = cent1[ck*9 + sv]; s1 += a*a;
        float b = cent2[ck*9 + sv]; s2 += b*b;
      }
      cn1[ck] = s1; cn2[ck] = s2;
      pool[ck] = 0.f;                 // ws is re-poisoned 0xAA every launch
    }
    float i1 = g1[t] * rsqrtf(va1[t] + 1e-5f);
    bn1i[t] = i1; bn1a[t] = be1[t] - mu1[t]*i1;
    float i2 = g2[t] * rsqrtf(va2[t] + 1e-5f);
    bn2i[t] = i2; bn2a[t] = be2[t] - mu2[t]*i2;
  }
}

// ---------------- attention conv1 (x in NCHW: lane=position is coalesced) ----------------
// sbuf stride 257: write phase quad reads hit banks r+q+{0,4,..,28} -> 2/bank (free).
__global__ __launch_bounds__(256) void attn0_kernel(
    const float* __restrict__ src, const float* __restrict__ cent,
    const float* __restrict__ cn, f16* __restrict__ attn)
{
  __shared__ uint32_t sbuf[16*257];
  int t = threadIdx.x;
  int P = blockIdx.x*256 + t;         // 0..12543
  int b = P / 784, n = P % 784, h = n / 28, w = n % 28;
  int c0 = blockIdx.y*2;
  int offc[9]; float msk[9];
#pragma unroll
  for (int dh = 0; dh < 3; ++dh)
#pragma unroll
    for (int dw = 0; dw < 3; ++dw) {
      int hh = h + dh - 1, ww = w + dw - 1;
      bool ok = (hh >= 0) && (hh < 28) && (ww >= 0) && (ww < 28);
      offc[dh*3+dw] = ok ? (hh*28 + ww) : 0;
      msk[dh*3+dw] = ok ? 1.f : 0.f;
    }
#pragma unroll
  for (int cc = 0; cc < 2; ++cc) {
    int c = c0 + cc;
    float p[9];
#pragma unroll
    for (int s = 0; s < 9; ++s)
      p[s] = src[(size_t)(b*256 + c)*784 + offc[s]] * msk[s];
    float e[16];
#pragma unroll
    for (int k = 0; k < 16; ++k) {
      const float* ce = cent + (size_t)(c*16 + k)*9;
      float dot = 0.f;
#pragma unroll
      for (int s = 0; s < 9; ++s) dot += p[s]*ce[s];
      e[k] = 2.f*dot - cn[c*16 + k];   // ||p||^2 cancels in softmax
    }
    float mx = e[0];
#pragma unroll
    for (int k = 1; k < 16; ++k) mx = fmaxf(mx, e[k]);
    float sum = 0.f;
#pragma unroll
    for (int k = 0; k < 16; ++k) { e[k] = __expf(e[k] - mx); sum += e[k]; }
    float r = 1.f / sum;
#pragma unroll
    for (int j = 0; j < 8; ++j)
      sbuf[(cc*8 + j)*257 + t] = packh2(e[2*j]*r, e[2*j+1]*r);
  }
  __syncthreads();
  // write phase: 4 lanes complete one 64B line (one position's 32 fp16)
  int seg = t & 3;
#pragma unroll
  for (int i = 0; i < 4; ++i) {
    int r = i*64 + (t >> 2);
    uint4 v = make_uint4(sbuf[(seg*4+0)*257 + r], sbuf[(seg*4+1)*257 + r],
                         sbuf[(seg*4+2)*257 + r], sbuf[(seg*4+3)*257 + r]);
    *(uint4*)(attn + (size_t)(blockIdx.x*256 + r)*4096 + c0*16 + seg*8) = v;
  }
}

// ---------------- attention conv2 (y1 in NHWC: LDS slab + LDS write exchange) ----------------
// Block = 256 positions x 16 channels; slab 314 rows x 16 ch (pad 17).
// sbuf stride 257 (same bank fix as attn0).
__global__ __launch_bounds__(256) void attn1_kernel(
    const float* __restrict__ src, const float* __restrict__ cent,
    const float* __restrict__ cn, f16* __restrict__ attn)
{
  __shared__ float ytile[314*17];
  __shared__ uint32_t sbuf[16*257];
  int t = threadIdx.x;
  int P0 = blockIdx.x*256;
  int c0 = blockIdx.y*16;
#pragma unroll
  for (int rr = 0; rr < 20; ++rr) {
    int r = rr*16 + (t >> 4);
    if (r < 314) {
      int gp = P0 - 29 + r;
      gp = min(max(gp, 0), 12543);
      ytile[r*17 + (t & 15)] = src[(size_t)gp*256 + c0 + (t & 15)];
    }
  }
  __syncthreads();
  int P = P0 + t;
  int n = P % 784, h = n / 28, w = n % 28;
  int dof[9]; int mb = 0;
#pragma unroll
  for (int dh = 0; dh < 3; ++dh)
#pragma unroll
    for (int dw = 0; dw < 3; ++dw) {
      int hh = h + dh - 1, ww = w + dw - 1;
      bool ok = (hh >= 0) && (hh < 28) && (ww >= 0) && (ww < 28);
      mb |= (ok ? 1 : 0) << (dh*3 + dw);
      dof[dh*3+dw] = (t + dh*28 + dw)*17;   // tile row offset (row 0 = P0-29)
    }
  int seg = t & 3;
#pragma unroll 1
  for (int cp = 0; cp < 8; ++cp) {
#pragma unroll
    for (int cc = 0; cc < 2; ++cc) {
      int cl = cp*2 + cc;
      int c = c0 + cl;
      float p[9];
#pragma unroll
      for (int s = 0; s < 9; ++s)
        p[s] = ((mb >> s) & 1) ? ytile[dof[s] + cl] : 0.f;
      float e[16];
#pragma unroll
      for (int k = 0; k < 16; ++k) {
        const float* ce = cent + (size_t)(c*16 + k)*9;
        float dot = 0.f;
#pragma unroll
        for (int s = 0; s < 9; ++s) dot += p[s]*ce[s];
        e[k] = 2.f*dot - cn[c*16 + k];
      }
      float mx = e[0];
#pragma unroll
      for (int k = 1; k < 16; ++k) mx = fmaxf(mx, e[k]);
      float sum = 0.f;
#pragma unroll
      for (int k = 0; k < 16; ++k) { e[k] = __expf(e[k] - mx); sum += e[k]; }
      float r = 1.f / sum;
#pragma unroll
      for (int j = 0; j < 8; ++j)
        sbuf[(cc*8 + j)*257 + t] = packh2(e[2*j]*r, e[2*j+1]*r);
    }
    __syncthreads();
#pragma unroll
    for (int i = 0; i < 4; ++i) {
      int r = i*64 + (t >> 2);
      uint4 v = make_uint4(sbuf[(seg*4+0)*257 + r], sbuf[(seg*4+1)*257 + r],
                           sbuf[(seg*4+2)*257 + r], sbuf[(seg*4+3)*257 + r]);
      *(uint4*)(attn + (size_t)(P0 + r)*4096 + (c0 + cp*2)*16 + seg*8) = v;
    }
    __syncthreads();   // sbuf reused next cp
  }
}

// ---------------- GEMM: C[12544,256] = A[12544,4096] * BT[256,4096]^T, fused BN ----------------
// R4 structure (measured 55.6us): BM=64, BN=64, BK=128, 256 threads, 4-way wave
// K-split, 784 blocks (3/CU). Reduction stride padded 68.
// EPI=0 (conv1): ReLU, write y1 NHWC [P][256] (attn1 slab needs NHWC).
// EPI=1 (conv2): write y2 NCHW [(b*256+o)*784+hw] as float4 (rows are 4-aligned,
//   784%4==0 -> never straddles b) + fused global-avg-pool partials via atomicAdd.
template<int EPI>
__global__ __launch_bounds__(256, 3) void gemm_kernel(
    const f16* __restrict__ A, const f16* __restrict__ BT,
    const float* __restrict__ inv, const float* __restrict__ add,
    float* __restrict__ Cout, float* __restrict__ pool)
{
  __shared__ __align__(16) char smem_raw[2*64*68*4];  // 34816B >= 32KB staging
  f16* As = (f16*)smem_raw;
  f16* Bs = (f16*)smem_raw + 8192;
  int bx = blockIdx.x;
  int xcd = bx & 7, i = bx >> 3;
  int nt4 = i & 3, j = i >> 2;
  int mt = xcd + 8*j;                 // same-A blocks (4 n-tiles) share an XCD for L2 reuse
  if (mt >= 196) return;
  int row0 = mt*64, col0 = nt4*64;
  int t = threadIdx.x;
  int lane = t & 63, wave = t >> 6;   // wave == k-quarter owner
  int fm = lane & 15, fq = lane >> 4;

  int jg = (t & 15) ^ ((t >> 4) & 7);
  const f16* Ag = A  + (size_t)(row0 + (t >> 4))*4096 + jg*8;
  const f16* Bg = BT + (size_t)(col0 + (t >> 4))*4096 + jg*8;
  f16* Al = As + t*8;
  f16* Bl = Bs + t*8;

  f32x4 acc[4][4] = {};

  int coff = ((wave*4 + fq) ^ (fm & 7)) * 8;
  const f16* a_rd = As + fm*128 + coff;
  const f16* b_rd = Bs + fm*128 + coff;

  for (int kt = 0; kt < 32; ++kt) {
    int kb = kt*128;
#pragma unroll
    for (int ii = 0; ii < 4; ++ii) {
      gload16(Ag + (size_t)(ii*16)*4096 + kb, Al + ii*2048);
      gload16(Bg + (size_t)(ii*16)*4096 + kb, Bl + ii*2048);
    }
    __syncthreads();
    f16x8 af[4], bf[4];
#pragma unroll
    for (int m2 = 0; m2 < 4; ++m2) af[m2] = *(const f16x8*)(a_rd + m2*16*128);
#pragma unroll
    for (int nt = 0; nt < 4; ++nt) bf[nt] = *(const f16x8*)(b_rd + nt*16*128);
#pragma unroll
    for (int m2 = 0; m2 < 4; ++m2)
#pragma unroll
      for (int nt = 0; nt < 4; ++nt)
        acc[m2][nt] = __builtin_amdgcn_mfma_f32_16x16x32_f16(af[m2], bf[nt], acc[m2][nt], 0, 0, 0);
    __syncthreads();
  }

  // cross-wave K reduction (4 partials -> wave 0), padded stride 68
  float* red = (float*)smem_raw;      // 2 x 64*68 f32
  if (wave >= 2) {
    float* dst = red + (wave - 2)*4352;
#pragma unroll
    for (int m2 = 0; m2 < 4; ++m2)
#pragma unroll
      for (int nt = 0; nt < 4; ++nt)
#pragma unroll
        for (int r = 0; r < 4; ++r)
          dst[(m2*16 + fq*4 + r)*68 + nt*16 + fm] = acc[m2][nt][r];
  }
  __syncthreads();
  if (wave < 2) {
    const float* s = red + wave*4352;
#pragma unroll
    for (int m2 = 0; m2 < 4; ++m2)
#pragma unroll
      for (int nt = 0; nt < 4; ++nt)
#pragma unroll
        for (int r = 0; r < 4; ++r)
          acc[m2][nt][r] += s[(m2*16 + fq*4 + r)*68 + nt*16 + fm];
  }
  __syncthreads();
  if (wave == 1) {
#pragma unroll
    for (int m2 = 0; m2 < 4; ++m2)
#pragma unroll
      for (int nt = 0; nt < 4; ++nt)
#pragma unroll
        for (int r = 0; r < 4; ++r)
          red[(m2*16 + fq*4 + r)*68 + nt*16 + fm] = acc[m2][nt][r];
  }
  __syncthreads();
  if (wave == 0) {
#pragma unroll
    for (int nt = 0; nt < 4; ++nt) {
      int colg = col0 + nt*16 + fm;   // C/D: col = lane&15
      float iv = inv[colg], ad = add[colg];
#pragma unroll
      for (int m2 = 0; m2 < 4; ++m2) {
        int rowl = m2*16 + fq*4;      // C/D: row = quad*4 + reg
        int P = row0 + rowl;
        if (EPI == 0) {
#pragma unroll
          for (int r = 0; r < 4; ++r) {
            float v = (acc[m2][nt][r] + red[(rowl + r)*68 + nt*16 + fm])*iv + ad;
            Cout[(size_t)(P + r)*256 + colg] = fmaxf(v, 0.f);
          }
        } else {
          int b = P / 784, hw = P % 784;
          f32x4 vv; float s4 = 0.f;
#pragma unroll
          for (int r = 0; r < 4; ++r) {
            float v = (acc[m2][nt][r] + red[(rowl + r)*68 + nt*16 + fm])*iv + ad;
            vv[r] = v; s4 += v;
          }
          *(f32x4*)(Cout + (size_t)(b*256 + colg)*784 + hw) = vv;
          atomicAdd(&pool[b*256 + colg], s4);
        }
      }
    }
  }
}

// ---------------- SE MLP: scale = sigmoid(relu(mean @ w1 + b1) @ w2 + b2) ----------------
__global__ __launch_bounds__(256) void se_kernel(
    const float* __restrict__ pool, const float* __restrict__ w1, const float* __restrict__ b1,
    const float* __restrict__ w2, const float* __restrict__ b2, float* __restrict__ scale)
{
  __shared__ float m[256];
  __shared__ float hbuf[16];
  int b = blockIdx.x, t = threadIdx.x;
  m[t] = pool[b*256 + t] * (1.f/784.f);
  __syncthreads();
  if (t < 16) {
    float a = b1[t];
    for (int o = 0; o < 256; ++o) a += m[o]*w1[o*16 + t];
    hbuf[t] = fmaxf(a, 0.f);
  }
  __syncthreads();
  float a = b2[t];
#pragma unroll
  for (int jj = 0; jj < 16; ++jj) a += hbuf[jj]*w2[jj*256 + t];
  scale[b*256 + t] = 1.f/(1.f + __expf(-a));
}

// ---------------- final: out = relu(y2 * scale + x), all NCHW (fully coalesced) ----------------
__global__ __launch_bounds__(256) void final_kernel(
    const float* __restrict__ y2, const float* __restrict__ scale,
    const float* __restrict__ x, float* __restrict__ out)
{
  int idx = blockIdx.x*256 + threadIdx.x;
  int bo = idx / 784;                  // flat NCHW: idx = (b*256+o)*784 + hw
  float v = y2[idx]*scale[bo] + x[idx];
  out[idx] = fmaxf(v, 0.f);
}

// ---------------- launch ----------------
extern "C" void kernel_launch(void* const* d_in, const int* in_sizes, int n_in,
                              void* d_out, int out_size, void* d_ws, size_t ws_size,
                              hipStream_t stream) {
  const float* x     = (const float*)d_in[0];
  const float* cent1 = (const float*)d_in[1];
  const float* wsub1 = (const float*)d_in[2];
  const float* g1    = (const float*)d_in[3];
  const float* be1   = (const float*)d_in[4];
  const float* mu1   = (const float*)d_in[5];
  const float* va1   = (const float*)d_in[6];
  const float* cent2 = (const float*)d_in[7];
  const float* wsub2 = (const float*)d_in[8];
  const float* g2    = (const float*)d_in[9];
  const float* be2   = (const float*)d_in[10];
  const float* mu2   = (const float*)d_in[11];
  const float* va2   = (const float*)d_in[12];
  const float* sw1   = (const float*)d_in[13];
  const float* sb1   = (const float*)d_in[14];
  const float* sw2   = (const float*)d_in[15];
  const float* sb2   = (const float*)d_in[16];
  float* out = (float*)d_out;

  char* ws = (char*)d_ws;
  f16*   attn  = (f16*)(ws + 0);                  // 12544*4096*2 = 102,760,448
  f16*   lut1T = (f16*)(ws + 102760448);          // 2 MB
  f16*   lut2T = (f16*)(ws + 104857600);          // 2 MB
  float* y1    = (float*)(ws + 106954752);        // 12,845,056 (NHWC)
  float* y2    = (float*)(ws + 119799808);        // 12,845,056 (NCHW)
  float* cn1   = (float*)(ws + 132644864);        // 16 KB
  float* cn2   = (float*)(ws + 132661248);        // 16 KB
  float* bn1i  = (float*)(ws + 132677632);
  float* bn1a  = (float*)(ws + 132678656);
  float* bn2i  = (float*)(ws + 132679680);
  float* bn2a  = (float*)(ws + 132680704);
  float* pool  = (float*)(ws + 132681728);        // 16 KB
  float* scale = (float*)(ws + 132698112);        // 16 KB  (end ~126.6 MiB)

  prep_kernel<<<513, 256, 0, stream>>>(cent1, wsub1, cent2, wsub2,
                                       g1, be1, mu1, va1, g2, be2, mu2, va2,
                                       lut1T, lut2T, cn1, cn2,
                                       bn1i, bn1a, bn2i, bn2a, pool);
  attn0_kernel<<<dim3(49, 128), 256, 0, stream>>>(x, cent1, cn1, attn);
  gemm_kernel<0><<<800, 256, 0, stream>>>(attn, lut1T, bn1i, bn1a, y1, nullptr);
  attn1_kernel<<<dim3(49, 16), 256, 0, stream>>>(y1, cent2, cn2, attn);
  gemm_kernel<1><<<800, 256, 0, stream>>>(attn, lut2T, bn2i, bn2a, y2, pool);
  se_kernel<<<16, 256, 0, stream>>>(pool, sw1, sb1, sw2, sb2, scale);
  final_kernel<<<12544, 256, 0, stream>>>(y2, scale, x, out);
}

// Round 10
// 328.283 us; speedup vs baseline: 1.1097x; 1.1097x over previous
//
#include <hip/hip_runtime.h>
#include <cstdint>
#include <cstddef>

typedef _Float16 f16;
typedef _Float16 f16x8 __attribute__((ext_vector_type(8)));
typedef float f32x4 __attribute__((ext_vector_type(4)));

// ---------------- helpers ----------------

__device__ __forceinline__ void gload16(const void* g, void* l) {
  // async global->LDS, 16B per lane; LDS dest must be wave-uniform base + lane*16
  __builtin_amdgcn_global_load_lds((const __attribute__((address_space(1))) void*)g,
                                   (__attribute__((address_space(3))) void*)l, 16, 0, 0);
}

__device__ __forceinline__ uint32_t packh2(float a, float b) {
  f16 ha = (f16)a, hb = (f16)b;
  uint16_t ua = __builtin_bit_cast(uint16_t, ha);
  uint16_t ub = __builtin_bit_cast(uint16_t, hb);
  return (uint32_t)ua | ((uint32_t)ub << 16);
}

// ---------------- prep: LUT^T fp16, centroid sq-norms, BN consts, pool zero ----------------
// bx<512: lut columns (coalesced 32B/thread stores).
// bx 512..543: cn1/cn2 parallelized 16 blocks each (the old single-block tail
// ran ~36k uncoalesced loads on ONE CU — a hidden ~50us serial stage).
// bx==544: bn consts + pool zero.
__global__ __launch_bounds__(256) void prep_kernel(
    const float* __restrict__ cent1, const float* __restrict__ wsub1,
    const float* __restrict__ cent2, const float* __restrict__ wsub2,
    const float* __restrict__ g1, const float* __restrict__ be1,
    const float* __restrict__ mu1, const float* __restrict__ va1,
    const float* __restrict__ g2, const float* __restrict__ be2,
    const float* __restrict__ mu2, const float* __restrict__ va2,
    f16* __restrict__ lut1T, f16* __restrict__ lut2T,
    float* __restrict__ cn1, float* __restrict__ cn2,
    float* __restrict__ bn1i, float* __restrict__ bn1a,
    float* __restrict__ bn2i, float* __restrict__ bn2a,
    float* __restrict__ pool)
{
  int bx = blockIdx.x, t = threadIdx.x;
  if (bx < 512) {
    int conv = bx >> 8, o = bx & 255;
    const float* cent = conv ? cent2 : cent1;
    const float* wsub = conv ? wsub2 : wsub1;
    f16* lutT = conv ? lut2T : lut1T;
    float wcol[9];
#pragma unroll
    for (int s = 0; s < 9; ++s) wcol[s] = wsub[(t*9 + s)*256 + o];
    uint32_t u[8];
#pragma unroll
    for (int k2 = 0; k2 < 8; ++k2) {
      float d0 = 0.f, d1 = 0.f;
#pragma unroll
      for (int s = 0; s < 9; ++s) {
        d0 += cent[(t*16 + 2*k2    )*9 + s]*wcol[s];
        d1 += cent[(t*16 + 2*k2 + 1)*9 + s]*wcol[s];
      }
      u[k2] = packh2(d0, d1);
    }
    uint4* dst = (uint4*)(lutT + (size_t)o*4096 + t*16);
    dst[0] = make_uint4(u[0], u[1], u[2], u[3]);
    dst[1] = make_uint4(u[4], u[5], u[6], u[7]);
  } else if (bx < 544) {
    int i = bx - 512;                 // 0..31: conv = i>>4, sub-block = i&15
    const float* cent = (i < 16) ? cent1 : cent2;
    float* cn = (i < 16) ? cn1 : cn2;
    int ck = (i & 15)*256 + t;
    float s = 0.f;
#pragma unroll
    for (int sv = 0; sv < 9; ++sv) {
      float a = cent[ck*9 + sv]; s += a*a;
    }
    cn[ck] = s;
  } else {
    for (int j = 0; j < 16; ++j) pool[j*256 + t] = 0.f;  // ws re-poisoned 0xAA
    float i1 = g1[t] * rsqrtf(va1[t] + 1e-5f);
    bn1i[t] = i1; bn1a[t] = be1[t] - mu1[t]*i1;
    float i2 = g2[t] * rsqrtf(va2[t] + 1e-5f);
    bn2i[t] = i2; bn2a[t] = be2[t] - mu2[t]*i2;
  }
}

// ---------------- attention conv1 (x in NCHW: lane=position is coalesced) ----------------
// sbuf stride 257: write phase quad reads 2 lanes/bank (free).
__global__ __launch_bounds__(256) void attn0_kernel(
    const float* __restrict__ src, const float* __restrict__ cent,
    const float* __restrict__ cn, f16* __restrict__ attn)
{
  __shared__ uint32_t sbuf[16*257];
  int t = threadIdx.x;
  int P = blockIdx.x*256 + t;         // 0..12543
  int b = P / 784, n = P % 784, h = n / 28, w = n % 28;
  int c0 = blockIdx.y*2;
  int offc[9]; float msk[9];
#pragma unroll
  for (int dh = 0; dh < 3; ++dh)
#pragma unroll
    for (int dw = 0; dw < 3; ++dw) {
      int hh = h + dh - 1, ww = w + dw - 1;
      bool ok = (hh >= 0) && (hh < 28) && (ww >= 0) && (ww < 28);
      offc[dh*3+dw] = ok ? (hh*28 + ww) : 0;
      msk[dh*3+dw] = ok ? 1.f : 0.f;
    }
#pragma unroll
  for (int cc = 0; cc < 2; ++cc) {
    int c = c0 + cc;
    float p[9];
#pragma unroll
    for (int s = 0; s < 9; ++s)
      p[s] = src[(size_t)(b*256 + c)*784 + offc[s]] * msk[s];
    float e[16];
#pragma unroll
    for (int k = 0; k < 16; ++k) {
      const float* ce = cent + (size_t)(c*16 + k)*9;
      float dot = 0.f;
#pragma unroll
      for (int s = 0; s < 9; ++s) dot += p[s]*ce[s];
      e[k] = 2.f*dot - cn[c*16 + k];   // ||p||^2 cancels in softmax
    }
    float mx = e[0];
#pragma unroll
    for (int k = 1; k < 16; ++k) mx = fmaxf(mx, e[k]);
    float sum = 0.f;
#pragma unroll
    for (int k = 0; k < 16; ++k) { e[k] = __expf(e[k] - mx); sum += e[k]; }
    float r = 1.f / sum;
#pragma unroll
    for (int j = 0; j < 8; ++j)
      sbuf[(cc*8 + j)*257 + t] = packh2(e[2*j]*r, e[2*j+1]*r);
  }
  __syncthreads();
  // write phase: 4 lanes complete one 64B line (one position's 32 fp16)
  int seg = t & 3;
#pragma unroll
  for (int i = 0; i < 4; ++i) {
    int r = i*64 + (t >> 2);
    uint4 v = make_uint4(sbuf[(seg*4+0)*257 + r], sbuf[(seg*4+1)*257 + r],
                         sbuf[(seg*4+2)*257 + r], sbuf[(seg*4+3)*257 + r]);
    *(uint4*)(attn + (size_t)(blockIdx.x*256 + r)*4096 + c0*16 + seg*8) = v;
  }
}

// ---------------- attention conv2 (y1 in NHWC: LDS slab + LDS write exchange) ----------------
__global__ __launch_bounds__(256) void attn1_kernel(
    const float* __restrict__ src, const float* __restrict__ cent,
    const float* __restrict__ cn, f16* __restrict__ attn)
{
  __shared__ float ytile[314*17];
  __shared__ uint32_t sbuf[16*257];
  int t = threadIdx.x;
  int P0 = blockIdx.x*256;
  int c0 = blockIdx.y*16;
#pragma unroll
  for (int rr = 0; rr < 20; ++rr) {
    int r = rr*16 + (t >> 4);
    if (r < 314) {
      int gp = P0 - 29 + r;
      gp = min(max(gp, 0), 12543);
      ytile[r*17 + (t & 15)] = src[(size_t)gp*256 + c0 + (t & 15)];
    }
  }
  __syncthreads();
  int P = P0 + t;
  int n = P % 784, h = n / 28, w = n % 28;
  int dof[9]; int mb = 0;
#pragma unroll
  for (int dh = 0; dh < 3; ++dh)
#pragma unroll
    for (int dw = 0; dw < 3; ++dw) {
      int hh = h + dh - 1, ww = w + dw - 1;
      bool ok = (hh >= 0) && (hh < 28) && (ww >= 0) && (ww < 28);
      mb |= (ok ? 1 : 0) << (dh*3 + dw);
      dof[dh*3+dw] = (t + dh*28 + dw)*17;   // tile row offset (row 0 = P0-29)
    }
  int seg = t & 3;
#pragma unroll 1
  for (int cp = 0; cp < 8; ++cp) {
#pragma unroll
    for (int cc = 0; cc < 2; ++cc) {
      int cl = cp*2 + cc;
      int c = c0 + cl;
      float p[9];
#pragma unroll
      for (int s = 0; s < 9; ++s)
        p[s] = ((mb >> s) & 1) ? ytile[dof[s] + cl] : 0.f;
      float e[16];
#pragma unroll
      for (int k = 0; k < 16; ++k) {
        const float* ce = cent + (size_t)(c*16 + k)*9;
        float dot = 0.f;
#pragma unroll
        for (int s = 0; s < 9; ++s) dot += p[s]*ce[s];
        e[k] = 2.f*dot - cn[c*16 + k];
      }
      float mx = e[0];
#pragma unroll
      for (int k = 1; k < 16; ++k) mx = fmaxf(mx, e[k]);
      float sum = 0.f;
#pragma unroll
      for (int k = 0; k < 16; ++k) { e[k] = __expf(e[k] - mx); sum += e[k]; }
      float r = 1.f / sum;
#pragma unroll
      for (int j = 0; j < 8; ++j)
        sbuf[(cc*8 + j)*257 + t] = packh2(e[2*j]*r, e[2*j+1]*r);
    }
    __syncthreads();
#pragma unroll
    for (int i = 0; i < 4; ++i) {
      int r = i*64 + (t >> 2);
      uint4 v = make_uint4(sbuf[(seg*4+0)*257 + r], sbuf[(seg*4+1)*257 + r],
                           sbuf[(seg*4+2)*257 + r], sbuf[(seg*4+3)*257 + r]);
      *(uint4*)(attn + (size_t)(P0 + r)*4096 + (c0 + cp*2)*16 + seg*8) = v;
    }
    __syncthreads();   // sbuf reused next cp
  }
}

// ---------------- GEMM: C[12544,256] = A[12544,4096] * BT[256,4096]^T, fused BN (+ReLU) ----------------
// R4/R8 structure (measured 55-59us): BM=64, BN=64, BK=128, 256 threads, 4-way
// wave K-split, 784 blocks (3/CU), padded-68 reduction. NHWC output for BOTH
// convs (R9's NCHW scatter epilogue cost +28us: 64 partial-line RMWs/instr).
template<bool RELU>
__global__ __launch_bounds__(256, 3) void gemm_kernel(
    const f16* __restrict__ A, const f16* __restrict__ BT,
    const float* __restrict__ inv, const float* __restrict__ add,
    float* __restrict__ Cout)
{
  __shared__ __align__(16) char smem_raw[2*64*68*4];  // 34816B >= 32KB staging
  f16* As = (f16*)smem_raw;
  f16* Bs = (f16*)smem_raw + 8192;
  int bx = blockIdx.x;
  int xcd = bx & 7, i = bx >> 3;
  int nt4 = i & 3, j = i >> 2;
  int mt = xcd + 8*j;                 // same-A blocks (4 n-tiles) share an XCD for L2 reuse
  if (mt >= 196) return;
  int row0 = mt*64, col0 = nt4*64;
  int t = threadIdx.x;
  int lane = t & 63, wave = t >> 6;   // wave == k-quarter owner
  int fm = lane & 15, fq = lane >> 4;

  int jg = (t & 15) ^ ((t >> 4) & 7);
  const f16* Ag = A  + (size_t)(row0 + (t >> 4))*4096 + jg*8;
  const f16* Bg = BT + (size_t)(col0 + (t >> 4))*4096 + jg*8;
  f16* Al = As + t*8;
  f16* Bl = Bs + t*8;

  f32x4 acc[4][4] = {};

  int coff = ((wave*4 + fq) ^ (fm & 7)) * 8;
  const f16* a_rd = As + fm*128 + coff;
  const f16* b_rd = Bs + fm*128 + coff;

  for (int kt = 0; kt < 32; ++kt) {
    int kb = kt*128;
#pragma unroll
    for (int ii = 0; ii < 4; ++ii) {
      gload16(Ag + (size_t)(ii*16)*4096 + kb, Al + ii*2048);
      gload16(Bg + (size_t)(ii*16)*4096 + kb, Bl + ii*2048);
    }
    __syncthreads();
    f16x8 af[4], bf[4];
#pragma unroll
    for (int m2 = 0; m2 < 4; ++m2) af[m2] = *(const f16x8*)(a_rd + m2*16*128);
#pragma unroll
    for (int nt = 0; nt < 4; ++nt) bf[nt] = *(const f16x8*)(b_rd + nt*16*128);
#pragma unroll
    for (int m2 = 0; m2 < 4; ++m2)
#pragma unroll
      for (int nt = 0; nt < 4; ++nt)
        acc[m2][nt] = __builtin_amdgcn_mfma_f32_16x16x32_f16(af[m2], bf[nt], acc[m2][nt], 0, 0, 0);
    __syncthreads();
  }

  // cross-wave K reduction (4 partials -> wave 0), padded stride 68
  float* red = (float*)smem_raw;      // 2 x 64*68 f32
  if (wave >= 2) {
    float* dst = red + (wave - 2)*4352;
#pragma unroll
    for (int m2 = 0; m2 < 4; ++m2)
#pragma unroll
      for (int nt = 0; nt < 4; ++nt)
#pragma unroll
        for (int r = 0; r < 4; ++r)
          dst[(m2*16 + fq*4 + r)*68 + nt*16 + fm] = acc[m2][nt][r];
  }
  __syncthreads();
  if (wave < 2) {
    const float* s = red + wave*4352;
#pragma unroll
    for (int m2 = 0; m2 < 4; ++m2)
#pragma unroll
      for (int nt = 0; nt < 4; ++nt)
#pragma unroll
        for (int r = 0; r < 4; ++r)
          acc[m2][nt][r] += s[(m2*16 + fq*4 + r)*68 + nt*16 + fm];
  }
  __syncthreads();
  if (wave == 1) {
#pragma unroll
    for (int m2 = 0; m2 < 4; ++m2)
#pragma unroll
      for (int nt = 0; nt < 4; ++nt)
#pragma unroll
        for (int r = 0; r < 4; ++r)
          red[(m2*16 + fq*4 + r)*68 + nt*16 + fm] = acc[m2][nt][r];
  }
  __syncthreads();
  if (wave == 0) {
#pragma unroll
    for (int nt = 0; nt < 4; ++nt) {
      int colg = col0 + nt*16 + fm;   // C/D: col = lane&15
      float iv = inv[colg], ad = add[colg];
#pragma unroll
      for (int m2 = 0; m2 < 4; ++m2) {
        int rowl = m2*16 + fq*4;      // C/D: row = quad*4 + reg
#pragma unroll
        for (int r = 0; r < 4; ++r) {
          float v = (acc[m2][nt][r] + red[(rowl + r)*68 + nt*16 + fm])*iv + ad;
          if (RELU) v = fmaxf(v, 0.f);
          Cout[(size_t)(row0 + rowl + r)*256 + colg] = v;
        }
      }
    }
  }
}

// ---------------- global average pool (y2 NHWC, 256 blocks, 1 atomic/thread) ----------------
__global__ __launch_bounds__(256) void pool_kernel(const float* __restrict__ y2,
                                                   float* __restrict__ pool)
{
  int b = blockIdx.x >> 4, rt = blockIdx.x & 15;
  int t = threadIdx.x;
  float s = 0.f;
  for (int r = rt*49; r < rt*49 + 49; ++r)
    s += y2[((size_t)b*784 + r)*256 + t];
  atomicAdd(&pool[b*256 + t], s);
}

// ---------------- SE MLP: scale = sigmoid(relu(mean @ w1 + b1) @ w2 + b2) ----------------
__global__ __launch_bounds__(256) void se_kernel(
    const float* __restrict__ pool, const float* __restrict__ w1, const float* __restrict__ b1,
    const float* __restrict__ w2, const float* __restrict__ b2, float* __restrict__ scale)
{
  __shared__ float m[256];
  __shared__ float hbuf[16];
  int b = blockIdx.x, t = threadIdx.x;
  m[t] = pool[b*256 + t] * (1.f/784.f);
  __syncthreads();
  if (t < 16) {
    float a = b1[t];
    for (int o = 0; o < 256; ++o) a += m[o]*w1[o*16 + t];
    hbuf[t] = fmaxf(a, 0.f);
  }
  __syncthreads();
  float a = b2[t];
#pragma unroll
  for (int jj = 0; jj < 16; ++jj) a += hbuf[jj]*w2[jj*256 + t];
  scale[b*256 + t] = 1.f/(1.f + __expf(-a));
}

// ---------------- final: out = relu(y2*scale + x), NHWC->NCHW via LDS transpose ----------------
// Block = 16 positions x 256 channels (784 blocks, one (b, hw-tile) each).
// Read y2 NHWC coalesced (1KB/instr); write NCHW as 4x64B full segments/instr.
// Tile stride 260 -> both phases 2 lanes/bank (free).
__global__ __launch_bounds__(256) void final_kernel(
    const float* __restrict__ y2, const float* __restrict__ scale,
    const float* __restrict__ x, float* __restrict__ out)
{
  __shared__ float tile[16*260];
  int t = threadIdx.x;
  int b = blockIdx.x / 49, rt = blockIdx.x % 49;
  int P0 = b*784 + rt*16;
#pragma unroll
  for (int i = 0; i < 16; ++i)
    tile[i*260 + t] = y2[(size_t)(P0 + i)*256 + t];
  __syncthreads();
  int hw0 = rt*16, hwl = t & 15, og = t >> 4;
#pragma unroll
  for (int j = 0; j < 16; ++j) {
    int o = j*16 + og;
    float v = tile[hwl*260 + o];
    size_t idx = (size_t)(b*256 + o)*784 + hw0 + hwl;
    out[idx] = fmaxf(v*scale[b*256 + o] + x[idx], 0.f);
  }
}

// ---------------- launch ----------------
extern "C" void kernel_launch(void* const* d_in, const int* in_sizes, int n_in,
                              void* d_out, int out_size, void* d_ws, size_t ws_size,
                              hipStream_t stream) {
  const float* x     = (const float*)d_in[0];
  const float* cent1 = (const float*)d_in[1];
  const float* wsub1 = (const float*)d_in[2];
  const float* g1    = (const float*)d_in[3];
  const float* be1   = (const float*)d_in[4];
  const float* mu1   = (const float*)d_in[5];
  const float* va1   = (const float*)d_in[6];
  const float* cent2 = (const float*)d_in[7];
  const float* wsub2 = (const float*)d_in[8];
  const float* g2    = (const float*)d_in[9];
  const float* be2   = (const float*)d_in[10];
  const float* mu2   = (const float*)d_in[11];
  const float* va2   = (const float*)d_in[12];
  const float* sw1   = (const float*)d_in[13];
  const float* sb1   = (const float*)d_in[14];
  const float* sw2   = (const float*)d_in[15];
  const float* sb2   = (const float*)d_in[16];
  float* out = (float*)d_out;

  char* ws = (char*)d_ws;
  f16*   attn  = (f16*)(ws + 0);                  // 12544*4096*2 = 102,760,448
  f16*   lut1T = (f16*)(ws + 102760448);          // 2 MB
  f16*   lut2T = (f16*)(ws + 104857600);          // 2 MB
  float* y1    = (float*)(ws + 106954752);        // 12,845,056 (NHWC)
  float* y2    = (float*)(ws + 119799808);        // 12,845,056 (NHWC)
  float* cn1   = (float*)(ws + 132644864);        // 16 KB
  float* cn2   = (float*)(ws + 132661248);        // 16 KB
  float* bn1i  = (float*)(ws + 132677632);
  float* bn1a  = (float*)(ws + 132678656);
  float* bn2i  = (float*)(ws + 132679680);
  float* bn2a  = (float*)(ws + 132680704);
  float* pool  = (float*)(ws + 132681728);        // 16 KB
  float* scale = (float*)(ws + 132698112);        // 16 KB  (end ~126.6 MiB)

  prep_kernel<<<545, 256, 0, stream>>>(cent1, wsub1, cent2, wsub2,
                                       g1, be1, mu1, va1, g2, be2, mu2, va2,
                                       lut1T, lut2T, cn1, cn2,
                                       bn1i, bn1a, bn2i, bn2a, pool);
  attn0_kernel<<<dim3(49, 128), 256, 0, stream>>>(x, cent1, cn1, attn);
  gemm_kernel<true><<<800, 256, 0, stream>>>(attn, lut1T, bn1i, bn1a, y1);
  attn1_kernel<<<dim3(49, 16), 256, 0, stream>>>(y1, cent2, cn2, attn);
  gemm_kernel<false><<<800, 256, 0, stream>>>(attn, lut2T, bn2i, bn2a, y2);
  pool_kernel<<<256, 256, 0, stream>>>(y2, pool);
  se_kernel<<<16, 256, 0, stream>>>(pool, sw1, sb1, sw2, sb2, scale);
  final_kernel<<<784, 256, 0, stream>>>(y2, scale, x, out);
}